// Round 5
// baseline (696.252 us; speedup 1.0000x reference)
//
#include <hip/hip_runtime.h>
#include <hip/hip_bf16.h>

#define T_TOK 1024
#define H_DIM 1024
#define I_DIM 1408
#define NE 16
#define NEP 18   // 16 routed + 2 pseudo (shared expert = two I=1408 halves)
#define BM 256   // token rows per block (64 per wave)

typedef __attribute__((ext_vector_type(8))) __bf16 bf16x8;
typedef __attribute__((ext_vector_type(4))) float f32x4;

__device__ __forceinline__ bf16x8 cvt8(float4 a, float4 b) {
    bf16x8 r;
    r[0] = (__bf16)a.x; r[1] = (__bf16)a.y; r[2] = (__bf16)a.z; r[3] = (__bf16)a.w;
    r[4] = (__bf16)b.x; r[5] = (__bf16)b.y; r[6] = (__bf16)b.z; r[7] = (__bf16)b.w;
    return r;
}

// ---------------------------------------------------------------- gate ------
__global__ __launch_bounds__(64) void gate_kernel(
    const float* __restrict__ x, const float* __restrict__ gw,
    const float* __restrict__ gb,
    int* __restrict__ counts, int* __restrict__ etok, float* __restrict__ ew,
    int* __restrict__ slotrow)
{
    const int t = blockIdx.x;
    const int lane = threadIdx.x;
    float s[NE];
#pragma unroll
    for (int e = 0; e < NE; ++e) s[e] = 0.f;
    const float* xr = x + (size_t)t * H_DIM;
    for (int i = lane; i < H_DIM; i += 64) {
        float xv = xr[i];
#pragma unroll
        for (int e = 0; e < NE; ++e) s[e] += xv * gw[e * H_DIM + i];
    }
#pragma unroll
    for (int e = 0; e < NE; ++e) {
        for (int off = 32; off > 0; off >>= 1) s[e] += __shfl_xor(s[e], off);
    }
    if (lane == 0) {
        float scores[NE], sfc[NE];
#pragma unroll
        for (int e = 0; e < NE; ++e) {
            scores[e] = 1.f / (1.f + __expf(-s[e]));
            sfc[e] = scores[e] + gb[e];
        }
        float gsc[4];
#pragma unroll
        for (int g = 0; g < 4; ++g) {
            float m1 = -1e30f, m2 = -1e30f;
#pragma unroll
            for (int j = 0; j < 4; ++j) {
                float v = sfc[4 * g + j];
                if (v > m1) { m2 = m1; m1 = v; } else if (v > m2) { m2 = v; }
            }
            gsc[g] = m1 + m2;
        }
        int g1 = 0;
        for (int g = 1; g < 4; ++g) if (gsc[g] > gsc[g1]) g1 = g;
        int g2 = -1;
        for (int g = 0; g < 4; ++g) {
            if (g == g1) continue;
            if (g2 < 0 || gsc[g] > gsc[g2]) g2 = g;
        }
        float tmp[NE];
#pragma unroll
        for (int e = 0; e < NE; ++e) {
            int gg = e >> 2;
            tmp[e] = (gg == g1 || gg == g2) ? sfc[e] : 0.0f;
        }
        int idxs[4]; float wk[4]; float wsum = 0.f;
#pragma unroll
        for (int k = 0; k < 4; ++k) {
            int bi = 0;
            for (int e = 1; e < NE; ++e) if (tmp[e] > tmp[bi]) bi = e;
            idxs[k] = bi; wk[k] = scores[bi]; wsum += scores[bi];
            tmp[bi] = -1e30f;
        }
        float inv = 1.f / (wsum + 1e-20f);
        for (int k = 0; k < 4; ++k) {
            int e = idxs[k];
            int pos = atomicAdd(&counts[e], 1);
            etok[e * T_TOK + pos] = t;
            ew[e * T_TOK + pos] = wk[k] * inv;   // SCALE = 1.0
            slotrow[t * 4 + k] = e * T_TOK + pos;
        }
    }
}

// ---------------------------------------------------- x f32 -> bf16 ---------
__global__ __launch_bounds__(256) void cvtx_kernel(
    const float* __restrict__ x, __hip_bfloat16* __restrict__ x_bf)
{
    int i = (blockIdx.x * 256 + threadIdx.x) * 4;
    float4 v = ((const float4*)x)[i >> 2];
    x_bf[i + 0] = __float2bfloat16(v.x);
    x_bf[i + 1] = __float2bfloat16(v.y);
    x_bf[i + 2] = __float2bfloat16(v.z);
    x_bf[i + 3] = __float2bfloat16(v.w);
}

// ------------------------------------------------------------- gate/up ------
// Grid (22, ne, 4), 256 thr. Wave w owns rows [row0+64w, row0+64w+64) x 64 I.
// Barrier-free: every wave loads its own A and B fragments from global;
// B(k+1) f32 regs prefetched while MFMAs of k run. No LDS, no __syncthreads.
__global__ __launch_bounds__(256) void gateup_kernel(
    const __hip_bfloat16* __restrict__ x_bf,
    const float* __restrict__ gproj, const float* __restrict__ uproj,
    const float* __restrict__ sgw, const float* __restrict__ suw,
    const int* __restrict__ counts, const int* __restrict__ etok,
    __hip_bfloat16* __restrict__ act, int e0)
{
    const int slot = blockIdx.y;
    const int e = e0 + slot;
    const int cnt = (e < NE) ? counts[e] : T_TOK;
    const int w = threadIdx.x >> 6;
    const int wrow0 = blockIdx.z * BM + w * 64;
    if (wrow0 >= cnt) return;              // wave-level exit (down mirrors this)

    const int lane = threadIdx.x & 63;
    const int col = lane & 15, kq = lane >> 4;
    const int nb0 = blockIdx.x * 64;

    const float *wg, *wu;
    if (e < NE) {
        wg = gproj + (size_t)e * I_DIM * H_DIM;
        wu = uproj + (size_t)e * I_DIM * H_DIM;
    } else {
        wg = sgw + (size_t)(e - NE) * I_DIM * H_DIM;
        wu = suw + (size_t)(e - NE) * I_DIM * H_DIM;
    }

    const __hip_bfloat16* ap[4];
#pragma unroll
    for (int mi = 0; mi < 4; ++mi) {
        int gr = wrow0 + mi * 16 + col;
        int tok = (e < NE) ? ((gr < cnt) ? etok[e * T_TOK + gr] : 0) : gr;
        ap[mi] = x_bf + (size_t)tok * H_DIM + kq * 8;
    }
    const float* bgp[4];
    const float* bup[4];
#pragma unroll
    for (int ni = 0; ni < 4; ++ni) {
        bgp[ni] = wg + (size_t)(nb0 + ni * 16 + col) * H_DIM + kq * 8;
        bup[ni] = wu + (size_t)(nb0 + ni * 16 + col) * H_DIM + kq * 8;
    }

    f32x4 accg[4][4], accu[4][4];
#pragma unroll
    for (int mi = 0; mi < 4; ++mi)
#pragma unroll
        for (int ni = 0; ni < 4; ++ni) {
            accg[mi][ni] = (f32x4){0.f, 0.f, 0.f, 0.f};
            accu[mi][ni] = (f32x4){0.f, 0.f, 0.f, 0.f};
        }

    float4 gs[4][2], us[4][2];
#pragma unroll
    for (int ni = 0; ni < 4; ++ni) {
        gs[ni][0] = ((const float4*)bgp[ni])[0]; gs[ni][1] = ((const float4*)bgp[ni])[1];
        us[ni][0] = ((const float4*)bup[ni])[0]; us[ni][1] = ((const float4*)bup[ni])[1];
    }

    for (int k = 0; k < H_DIM / 32; ++k) {
        bf16x8 bg[4], bu[4];
#pragma unroll
        for (int ni = 0; ni < 4; ++ni) {
            bg[ni] = cvt8(gs[ni][0], gs[ni][1]);
            bu[ni] = cvt8(us[ni][0], us[ni][1]);
        }
        if (k < H_DIM / 32 - 1) {
#pragma unroll
            for (int ni = 0; ni < 4; ++ni) {
                const float4* pg = (const float4*)(bgp[ni] + (k + 1) * 32);
                const float4* pu = (const float4*)(bup[ni] + (k + 1) * 32);
                gs[ni][0] = pg[0]; gs[ni][1] = pg[1];
                us[ni][0] = pu[0]; us[ni][1] = pu[1];
            }
        }
        bf16x8 a[4];
#pragma unroll
        for (int mi = 0; mi < 4; ++mi) a[mi] = *(const bf16x8*)(ap[mi] + k * 32);
#pragma unroll
        for (int mi = 0; mi < 4; ++mi)
#pragma unroll
            for (int ni = 0; ni < 4; ++ni) {
                accg[mi][ni] = __builtin_amdgcn_mfma_f32_16x16x32_bf16(a[mi], bg[ni], accg[mi][ni], 0, 0, 0);
                accu[mi][ni] = __builtin_amdgcn_mfma_f32_16x16x32_bf16(a[mi], bu[ni], accu[mi][ni], 0, 0, 0);
            }
    }

    // epilogue: silu(g)*u (zeros on padded rows of the last active 64-group)
#pragma unroll
    for (int mi = 0; mi < 4; ++mi)
#pragma unroll
        for (int r = 0; r < 4; ++r) {
            int grow = wrow0 + mi * 16 + kq * 4 + r;
            bool live = grow < cnt;
#pragma unroll
            for (int ni = 0; ni < 4; ++ni) {
                float g = accg[mi][ni][r];
                float a = live ? (g / (1.f + __expf(-g)) * accu[mi][ni][r]) : 0.f;
                act[((size_t)slot * T_TOK + grow) * I_DIM + nb0 + ni * 16 + col] =
                    __float2bfloat16(a);
            }
        }
}

// ---------------------------------------------------------------- down ------
// Grid (16, ne, 4), 256 thr. Barrier-free like gateup. COMBINE: store weighted
// rows into dout[e*1024+row][H]; else atomicAdd into y[token][H].
template<bool COMBINE>
__global__ __launch_bounds__(256) void down_kernel(
    const __hip_bfloat16* __restrict__ act,
    const float* __restrict__ dproj, const float* __restrict__ sdw,
    const int* __restrict__ counts, const int* __restrict__ etok,
    const float* __restrict__ ew, float* __restrict__ y, int e0)
{
    const int slot = blockIdx.y;
    const int e = e0 + slot;
    const int cnt = (e < NE) ? counts[e] : T_TOK;
    const int w = threadIdx.x >> 6;
    const int wrow0 = blockIdx.z * BM + w * 64;
    if (wrow0 >= cnt) return;

    const int lane = threadIdx.x & 63;
    const int col = lane & 15, kq = lane >> 4;
    const int nb0 = blockIdx.x * 64;

    const float* wd;
    int wstride;
    if (e < NE) { wd = dproj + (size_t)e * H_DIM * I_DIM; wstride = I_DIM; }
    else        { wd = sdw + (size_t)(e - NE) * I_DIM;    wstride = 2 * I_DIM; }

    const __hip_bfloat16* ap[4];
#pragma unroll
    for (int mi = 0; mi < 4; ++mi)
        ap[mi] = act + ((size_t)slot * T_TOK + wrow0 + mi * 16 + col) * I_DIM + kq * 8;
    const float* bdp[4];
#pragma unroll
    for (int ni = 0; ni < 4; ++ni)
        bdp[ni] = wd + (size_t)(nb0 + ni * 16 + col) * wstride + kq * 8;

    f32x4 acc[4][4];
#pragma unroll
    for (int mi = 0; mi < 4; ++mi)
#pragma unroll
        for (int ni = 0; ni < 4; ++ni) acc[mi][ni] = (f32x4){0.f, 0.f, 0.f, 0.f};

    float4 ds[4][2];
#pragma unroll
    for (int ni = 0; ni < 4; ++ni) {
        ds[ni][0] = ((const float4*)bdp[ni])[0]; ds[ni][1] = ((const float4*)bdp[ni])[1];
    }

    for (int k = 0; k < I_DIM / 32; ++k) {
        bf16x8 bd[4];
#pragma unroll
        for (int ni = 0; ni < 4; ++ni) bd[ni] = cvt8(ds[ni][0], ds[ni][1]);
        if (k < I_DIM / 32 - 1) {
#pragma unroll
            for (int ni = 0; ni < 4; ++ni) {
                const float4* pd = (const float4*)(bdp[ni] + (k + 1) * 32);
                ds[ni][0] = pd[0]; ds[ni][1] = pd[1];
            }
        }
        bf16x8 a[4];
#pragma unroll
        for (int mi = 0; mi < 4; ++mi) a[mi] = *(const bf16x8*)(ap[mi] + k * 32);
#pragma unroll
        for (int mi = 0; mi < 4; ++mi)
#pragma unroll
            for (int ni = 0; ni < 4; ++ni)
                acc[mi][ni] = __builtin_amdgcn_mfma_f32_16x16x32_bf16(a[mi], bd[ni], acc[mi][ni], 0, 0, 0);
    }

#pragma unroll
    for (int mi = 0; mi < 4; ++mi)
#pragma unroll
        for (int r = 0; r < 4; ++r) {
            int grow = wrow0 + mi * 16 + kq * 4 + r;
            if (grow >= cnt) continue;
            if (COMBINE) {
                float wt = (e < NE) ? ew[e * T_TOK + grow] : 1.f;
#pragma unroll
                for (int ni = 0; ni < 4; ++ni)
                    y[((size_t)e * T_TOK + grow) * H_DIM + nb0 + ni * 16 + col] =
                        acc[mi][ni][r] * wt;
            } else {
                float wt; int tokr;
                if (e < NE) { wt = ew[e * T_TOK + grow]; tokr = etok[e * T_TOK + grow]; }
                else        { wt = 1.f;                  tokr = grow; }
#pragma unroll
                for (int ni = 0; ni < 4; ++ni)
                    atomicAdd(&y[(size_t)tokr * H_DIM + nb0 + ni * 16 + col],
                              acc[mi][ni][r] * wt);
            }
        }
}

// ------------------------------------------------------------- combine ------
// out[t][h] = sum of the token's 4 routed dout rows + 2 shared dout rows.
__global__ __launch_bounds__(256) void combine_kernel(
    const float* __restrict__ dout, const int* __restrict__ slotrow,
    float* __restrict__ out)
{
    const int t = blockIdx.x;
    const int h4 = threadIdx.x;                      // float4 index in [0,256)
    const float4* d4 = (const float4*)dout;
    float4 s0 = d4[((size_t)(16 * T_TOK + t)) * 256 + h4];
    float4 s1 = d4[((size_t)(17 * T_TOK + t)) * 256 + h4];
    float4 s = {s0.x + s1.x, s0.y + s1.y, s0.z + s1.z, s0.w + s1.w};
#pragma unroll
    for (int j = 0; j < 4; ++j) {
        int sr = slotrow[t * 4 + j];
        float4 v = d4[(size_t)sr * 256 + h4];
        s.x += v.x; s.y += v.y; s.z += v.z; s.w += v.w;
    }
    ((float4*)out)[(size_t)t * 256 + h4] = s;
}

// -------------------------------------------------------------- launch ------
extern "C" void kernel_launch(void* const* d_in, const int* in_sizes, int n_in,
                              void* d_out, int out_size, void* d_ws, size_t ws_size,
                              hipStream_t stream) {
    (void)in_sizes; (void)n_in; (void)out_size;
    const float* x  = (const float*)d_in[0];
    const float* gw = (const float*)d_in[1];
    const float* gb = (const float*)d_in[2];
    const float* gp = (const float*)d_in[3];
    const float* up = (const float*)d_in[4];
    const float* dp = (const float*)d_in[5];
    const float* sg = (const float*)d_in[6];
    const float* su = (const float*)d_in[7];
    const float* sd = (const float*)d_in[8];
    float* out = (float*)d_out;

    char* ws = (char*)d_ws;
    int*   counts  = (int*)ws;                                   // @0       256 B
    int*   slotrow = (int*)(ws + 256);                           // 16 KB
    int*   etok    = (int*)(ws + 16640);                         // 64 KB
    float* ew      = (float*)(ws + 82176);                       // 64 KB
    __hip_bfloat16* x_bf = (__hip_bfloat16*)(ws + 147712);       // 2 MB
    __hip_bfloat16* act  = (__hip_bfloat16*)(ws + 2244864);      // 49.5 MB
    float* dout    = (float*)(ws + 54149376);                    // 72 MB

    const size_t need_combine = 54149376ull + (size_t)NEP * T_TOK * H_DIM * 4;
    const bool combine = ws_size >= need_combine;

    hipMemsetAsync(ws, 0, 256, stream);                          // counts
    gate_kernel<<<dim3(T_TOK), dim3(64), 0, stream>>>(x, gw, gb, counts, etok, ew, slotrow);
    cvtx_kernel<<<dim3(1024), dim3(256), 0, stream>>>(x, x_bf);

    if (combine) {
        gateup_kernel<<<dim3(I_DIM / 64, NEP, T_TOK / BM), dim3(256), 0, stream>>>(
            x_bf, gp, up, sg, su, counts, etok, act, 0);
        down_kernel<true><<<dim3(H_DIM / 64, NEP, T_TOK / BM), dim3(256), 0, stream>>>(
            act, dp, sd, counts, etok, ew, dout, 0);
        combine_kernel<<<dim3(T_TOK), dim3(256), 0, stream>>>(dout, slotrow, out);
    } else {
        // fallback: atomic accumulation into out, expert chunking if ws small
        size_t fixed = 2244864;
        size_t per_e = (size_t)T_TOK * I_DIM * 2;                // 2.75 MB / slot
        int cap = NEP;
        if (ws_size < fixed + (size_t)NEP * per_e) {
            cap = (ws_size > fixed + per_e) ? (int)((ws_size - fixed) / per_e) : 1;
            if (cap < 1) cap = 1;
        }
        hipMemsetAsync(out, 0, (size_t)T_TOK * H_DIM * 4, stream);
        for (int e0 = 0; e0 < NEP; e0 += cap) {
            int ne = NEP - e0 < cap ? NEP - e0 : cap;
            gateup_kernel<<<dim3(I_DIM / 64, ne, T_TOK / BM), dim3(256), 0, stream>>>(
                x_bf, gp, up, sg, su, counts, etok, act, e0);
            down_kernel<false><<<dim3(H_DIM / 64, ne, T_TOK / BM), dim3(256), 0, stream>>>(
                act, dp, sd, counts, etok, ew, out, e0);
        }
    }
}